// Round 23
// baseline (132.353 us; speedup 1.0000x reference)
//
#include <hip/hip_runtime.h>
#include <hip/hip_bf16.h>

typedef __attribute__((ext_vector_type(4)))  float  f32x4;
typedef __attribute__((ext_vector_type(16))) float  f32x16;
typedef __attribute__((ext_vector_type(8)))  short  bf16x8;
typedef __attribute__((ext_vector_type(8)))  ushort u16x8;

#define C_DIM   384
#define QKV_DIM 1152
#define NHEAD   12
#define HDIM    32
#define NTOK    256

__device__ __forceinline__ ushort f2bf(float f) {
    union { __hip_bfloat16 h; ushort u; } cv;
    cv.h = __float2bfloat16(f);
    return cv.u;
}

// ---------------- fp32 -> bf16 convert (grid-strided, 8 elems/iter) ----------------
__global__ void cvt_kernel(const float* __restrict__ in, ushort* __restrict__ out, int n8) {
    const int stride = gridDim.x * blockDim.x;
    for (int i = blockIdx.x * blockDim.x + threadIdx.x; i < n8; i += stride) {
        const float4 v0 = reinterpret_cast<const float4*>(in)[2 * i];
        const float4 v1 = reinterpret_cast<const float4*>(in)[2 * i + 1];
        union { ushort u[8]; u16x8 v; } o;
        o.u[0] = f2bf(v0.x); o.u[1] = f2bf(v0.y);
        o.u[2] = f2bf(v0.z); o.u[3] = f2bf(v0.w);
        o.u[4] = f2bf(v1.x); o.u[5] = f2bf(v1.y);
        o.u[6] = f2bf(v1.z); o.u[7] = f2bf(v1.w);
        reinterpret_cast<u16x8*>(out)[i] = o.v;
    }
}

// ---------------- GEMM: C[M,N] = A[M,K]*B[N,K]^T (+bias), BK=64 ----------------
// 128x64 tile (r13 fragment algebra verbatim), TRIPLE-buffered LDS with
// 2-deep prefetch and ONE barrier per K-tile:
//   iter kt: vmcnt(6) [retire tile-kt loads; outstanding = kt,kt+1 = 12]
//            -> s_barrier [all waves' tile-kt loads visible; all waves done
//               reading buf(kt-1)] -> stage(kt+2 -> buf(kt-1)) -> compute(kt).
// Loads get ~2 iterations to land instead of one compute phase.
// Same K-accumulation order -> bit-identical output.
// AHB : A head-blocked [K/32][M][32] (att);  OHB : out head-blocked [36][M][32]
template<int BIAS, int OUTF32, int AHB, int OHB>
__global__ __launch_bounds__(256, 2) void gemm_bt(const ushort* __restrict__ A,
                                                  const ushort* __restrict__ Bw,
                                                  const float* __restrict__ bias,
                                                  void* __restrict__ Cout,
                                                  int M, int N, int K) {
    __shared__ __align__(16) ushort As[3][128 * 64];
    __shared__ __align__(16) ushort Bs[3][64 * 64];

    const int t    = threadIdx.x;
    const int lane = t & 63;
    const int wave = t >> 6;
    const int wr   = (wave >> 1) * 64;
    const int wc   = (wave & 1) * 32;
    const int lr   = lane & 15;
    const int lg   = lane >> 4;

    const int gx  = gridDim.x;
    const int nwg = gx * gridDim.y;
    const int hw  = blockIdx.y * gx + blockIdx.x;
    const int cpx = nwg >> 3;
    const int lin = (hw & 7) * cpx + (hw >> 3);
    const int by  = lin / gx;
    const int bx  = lin - by * gx;
    const int mBase = by * 128;
    const int nBase = bx * 64;

    f32x4 acc[4][2] = {};
    const int nK = K >> 6;          // 6 K-tiles at K=384

    auto stage = [&](int kt, int c) {               // 6 global_load_lds / thread
        const int k0 = kt << 6;
#pragma unroll
        for (int it = 0; it < 4; ++it) {            // A: 128 rows x 64 k
            const int idx = it * 256 + t;
            const int r   = idx >> 3;
            const int cb  = (idx & 7) ^ (r & 7);
            const ushort* ga;
            if (AHB) {
                const int k = k0 + cb * 8;
                ga = A + ((size_t)(k >> 5) * M + (mBase + r)) * 32 + (k & 31);
            } else {
                ga = A + (size_t)(mBase + r) * K + k0 + cb * 8;
            }
            __builtin_amdgcn_global_load_lds(
                (const __attribute__((address_space(1))) void*)ga,
                (__attribute__((address_space(3))) void*)(&As[c][it * 2048 + wave * 512]),
                16, 0, 0);
        }
#pragma unroll
        for (int it = 0; it < 2; ++it) {            // B: 64 rows x 64 k
            const int idx = it * 256 + t;
            const int r   = idx >> 3;
            const int cb  = (idx & 7) ^ (r & 7);
            const ushort* gb = Bw + (size_t)(nBase + r) * K + k0 + cb * 8;
            __builtin_amdgcn_global_load_lds(
                (const __attribute__((address_space(1))) void*)gb,
                (__attribute__((address_space(3))) void*)(&Bs[c][it * 2048 + wave * 512]),
                16, 0, 0);
        }
    };

    // prologue: 2 tiles in flight
    stage(0, 0);
    if (nK > 1) stage(1, 1);

    for (int kt = 0; kt < nK; ++kt) {
        if (kt + 1 < nK) {
            asm volatile("s_waitcnt vmcnt(6)" ::: "memory");  // tile-kt loads done (oldest 6 of 12)
        } else {
            asm volatile("s_waitcnt vmcnt(0)" ::: "memory");
        }
        __builtin_amdgcn_s_barrier();               // tile-kt visible; buf(kt-1) reads complete
        __builtin_amdgcn_sched_barrier(0);          // pin stage below the barrier

        if (kt + 2 < nK) stage(kt + 2, (kt + 2) % 3);
        __builtin_amdgcn_sched_barrier(0);          // pin compute below the stage issue

        const int cur = kt % 3;
#pragma unroll
        for (int kk = 0; kk < 2; ++kk) {
            bf16x8 af[4], bfr[2];
#pragma unroll
            for (int m = 0; m < 4; ++m) {
                const int r = wr + m * 16 + lr;
                af[m] = *reinterpret_cast<const bf16x8*>(
                    &As[cur][r * 64 + (((kk * 4 + lg) ^ (r & 7)) << 3)]);
            }
#pragma unroll
            for (int n = 0; n < 2; ++n) {
                const int r = wc + n * 16 + lr;
                bfr[n] = *reinterpret_cast<const bf16x8*>(
                    &Bs[cur][r * 64 + (((kk * 4 + lg) ^ (r & 7)) << 3)]);
            }
#pragma unroll
            for (int m = 0; m < 4; ++m)
#pragma unroll
                for (int n = 0; n < 2; ++n)
                    acc[m][n] = __builtin_amdgcn_mfma_f32_16x16x32_bf16(af[m], bfr[n], acc[m][n], 0, 0, 0);
        }
        __builtin_amdgcn_sched_barrier(0);          // keep compute's LDS reads above next barrier
    }

#pragma unroll
    for (int n = 0; n < 2; ++n) {
        const int col = nBase + wc + n * 16 + lr;
        const float bv = BIAS ? bias[col] : 0.f;
        const int sel  = OHB ? (col / 384) : 0;
        const int c384 = OHB ? (col - sel * 384) : 0;
#pragma unroll
        for (int m = 0; m < 4; ++m) {
            const int row0 = mBase + wr + m * 16 + lg * 4;
#pragma unroll
            for (int j = 0; j < 4; ++j) {
                const float v = acc[m][n][j] + bv;
                const int row = row0 + j;
                if (OUTF32) {
                    reinterpret_cast<float*>(Cout)[(size_t)row * N + col] = v;
                } else if (OHB) {
                    reinterpret_cast<ushort*>(Cout)[
                        ((size_t)(sel * NHEAD + (c384 >> 5)) * M + row) * 32 + (c384 & 31)] = f2bf(v);
                } else {
                    reinterpret_cast<ushort*>(Cout)[(size_t)row * N + col] = f2bf(v);
                }
            }
        }
    }
}

// ---------------- fused attention: one block per (window, head) ----------------
// r13-VERBATIM (8 waves x 512 threads, one 32-row chunk per wave; two-pass
// recompute, normalized-P single bf16 rounding).
__global__ __launch_bounds__(512) void attn_kernel(const ushort* __restrict__ qkv,
                                                   ushort* __restrict__ att,
                                                   int Mtok) {
    __shared__ __align__(16) ushort Ks[NTOK * HDIM];   // [key][d], swizzled 16B blocks
    __shared__ __align__(16) ushort Vt[HDIM * NTOK];   // [d][key], swizzled 16B blocks

    const int bid = blockIdx.x;
    const int win = bid / NHEAD;
    const int h   = bid % NHEAD;

    const int t    = threadIdx.x;
    const int lane = t & 63;
    const int wave = t >> 6;          // 0..7
    const int l31  = lane & 31;
    const int h5   = lane >> 5;

    const size_t winRow = (size_t)win * NTOK;
    const ushort* Qbase = qkv + ((size_t)h * Mtok + winRow) * HDIM;
    const ushort* Kbase = qkv + ((size_t)(NHEAD + h) * Mtok + winRow) * HDIM;
    const ushort* Vbase = qkv + ((size_t)(2 * NHEAD + h) * Mtok + winRow) * HDIM;

#pragma unroll
    for (int it = 0; it < 2; ++it) {
        const int idx = it * 512 + t;
        const int key = idx >> 2;
        const int cb  = (idx & 3) ^ (key & 3);
        const ushort* gk = Kbase + key * HDIM + cb * 8;
        __builtin_amdgcn_global_load_lds(
            (const __attribute__((address_space(1))) void*)gk,
            (__attribute__((address_space(3))) void*)(&Ks[it * 4096 + wave * 512]),
            16, 0, 0);
    }
#pragma unroll
    for (int it = 0; it < 2; ++it) {
        const int idx = it * 512 + t;
        const int key = idx >> 2;
        const int cb  = idx & 3;
        u16x8 v8 = *reinterpret_cast<const u16x8*>(Vbase + key * HDIM + cb * 8);
#pragma unroll
        for (int jj = 0; jj < 8; ++jj) {
            const int dd  = cb * 8 + jj;
            const int blk = (key >> 3) ^ (dd & 7) ^ ((2 * (dd >> 3)) & 6);
            Vt[dd * NTOK + blk * 8 + (key & 7)] = v8[jj];
        }
    }
    __syncthreads();

    const float c1   = 0.25503509f;                 // 32^-0.5 * log2(e)
    const int   vmsk = (l31 & 7) ^ ((2 * (l31 >> 3)) & 6);
    const int   kmsk = l31 & 3;
    const int   q0   = wave * 32;                   // one 32-row chunk per wave

    const int qrow = q0 + l31;
    const bf16x8 qf0 = *reinterpret_cast<const bf16x8*>(
        Qbase + (size_t)qrow * HDIM + h5 * 8);
    const bf16x8 qf1 = *reinterpret_cast<const bf16x8*>(
        Qbase + (size_t)qrow * HDIM + 16 + h5 * 8);

    // ---- pass 1: softmax denominator (score tile dies each iteration) ----
    float sm0 = 0.f, sm1 = 0.f, sm2 = 0.f, sm3 = 0.f;
#pragma unroll
    for (int tt = 0; tt < 8; ++tt) {
        const int key = tt * 32 + l31;
        const bf16x8 kf0 = *reinterpret_cast<const bf16x8*>(
            &Ks[key * HDIM + ((h5 ^ kmsk) << 3)]);
        const bf16x8 kf1 = *reinterpret_cast<const bf16x8*>(
            &Ks[key * HDIM + (((2 + h5) ^ kmsk) << 3)]);
        f32x16 s = {};
        s = __builtin_amdgcn_mfma_f32_32x32x16_bf16(kf0, qf0, s, 0, 0, 0);
        s = __builtin_amdgcn_mfma_f32_32x32x16_bf16(kf1, qf1, s, 0, 0, 0);
#pragma unroll
        for (int r = 0; r < 16; r += 4) {
            sm0 += __builtin_amdgcn_exp2f(s[r + 0] * c1);
            sm1 += __builtin_amdgcn_exp2f(s[r + 1] * c1);
            sm2 += __builtin_amdgcn_exp2f(s[r + 2] * c1);
            sm3 += __builtin_amdgcn_exp2f(s[r + 3] * c1);
        }
    }
    float sm = (sm0 + sm1) + (sm2 + sm3);
    sm += __shfl_xor(sm, 32, 64);
    const float inv = __builtin_amdgcn_rcpf(sm);

    // ---- pass 2: recompute QK, pack NORMALIZED P (fp32->bf16 once), PV ----
    f32x16 O = {};
#pragma unroll
    for (int tt = 0; tt < 8; ++tt) {
        const int key = tt * 32 + l31;
        const bf16x8 kf0 = *reinterpret_cast<const bf16x8*>(
            &Ks[key * HDIM + ((h5 ^ kmsk) << 3)]);
        const bf16x8 kf1 = *reinterpret_cast<const bf16x8*>(
            &Ks[key * HDIM + (((2 + h5) ^ kmsk) << 3)]);
        f32x16 s = {};
        s = __builtin_amdgcn_mfma_f32_32x32x16_bf16(kf0, qf0, s, 0, 0, 0);
        s = __builtin_amdgcn_mfma_f32_32x32x16_bf16(kf1, qf1, s, 0, 0, 0);

        uint pk8[8];
#pragma unroll
        for (int m = 0; m < 8; ++m) {
            const int r = 4 * (m >> 1) + 2 * (m & 1);
            const float lo = __builtin_amdgcn_exp2f(s[r + 0] * c1) * inv;
            const float hi = __builtin_amdgcn_exp2f(s[r + 1] * c1) * inv;
            uint d;
            asm("v_cvt_pk_bf16_f32 %0, %1, %2" : "=v"(d) : "v"(lo), "v"(hi));
            pk8[m] = d;
        }

        // PV: half of the P-fragment comes from partner lane^32 (r11-verbatim)
#pragma unroll
        for (int k16 = 0; k16 < 2; ++k16) {
            const int mb = 4 * k16;
            const uint s0 = h5 ? pk8[mb + 0] : pk8[mb + 2];
            const uint s1 = h5 ? pk8[mb + 1] : pk8[mb + 3];
            const uint x0 = (uint)__shfl_xor((int)s0, 32, 64);
            const uint x1 = (uint)__shfl_xor((int)s1, 32, 64);
            union { uint u[4]; bf16x8 v; } pw;
            pw.u[0] = h5 ? x0 : pk8[mb + 0];
            pw.u[1] = h5 ? x1 : pk8[mb + 1];
            pw.u[2] = h5 ? pk8[mb + 2] : x0;
            pw.u[3] = h5 ? pk8[mb + 3] : x1;
            const int blk = (4 * tt + 2 * k16 + h5) ^ vmsk;
            const bf16x8 vf = *reinterpret_cast<const bf16x8*>(
                &Vt[l31 * NTOK + blk * 8]);
            O = __builtin_amdgcn_mfma_f32_32x32x16_bf16(pw.v, vf, O, 0, 0, 0);
        }
    }

    // ---- store (r3-verbatim): row=(r&3)+8(r>>2)+4h5, col d=l31 ----
    ushort* obase = att + ((size_t)h * Mtok + winRow + q0) * HDIM + l31;
#pragma unroll
    for (int r = 0; r < 16; ++r) {
        const int qr = (r & 3) + 8 * (r >> 2) + 4 * h5;
        obase[(size_t)qr * HDIM] = f2bf(O[r]);
    }
}

// ---------------- host ----------------
extern "C" void kernel_launch(void* const* d_in, const int* in_sizes, int n_in,
                              void* d_out, int out_size, void* d_ws, size_t ws_size,
                              hipStream_t stream) {
    const float* x     = (const float*)d_in[0];
    const float* w_in  = (const float*)d_in[1];
    const float* b_in  = (const float*)d_in[2];
    const float* w_out = (const float*)d_in[3];

    const int M    = in_sizes[0] / C_DIM;  // 32768 tokens
    const int nWin = M / NTOK;             // 128 windows

    char* ws = (char*)d_ws;
    size_t off = 0;
    ushort* xb    = (ushort*)(ws + off); off += (size_t)M * C_DIM * 2;
    ushort* qkvb  = (ushort*)(ws + off); off += (size_t)M * QKV_DIM * 2;   // [36][M][32]
    ushort* attb  = (ushort*)(ws + off); off += (size_t)M * C_DIM * 2;     // [12][M][32]
    ushort* wqkvb = (ushort*)(ws + off); off += (size_t)QKV_DIM * C_DIM * 2;
    ushort* woutb = (ushort*)(ws + off);

    // grid-strided converts (8 elems/thread-iter, 16B stores)
    cvt_kernel<<<2048, 256, 0, stream>>>(x, xb, M * C_DIM / 8);
    cvt_kernel<<<(QKV_DIM * C_DIM / 8 + 255) / 256, 256, 0, stream>>>(
        w_in, wqkvb, QKV_DIM * C_DIM / 8);
    cvt_kernel<<<(C_DIM * C_DIM / 8 + 255) / 256, 256, 0, stream>>>(
        w_out, woutb, C_DIM * C_DIM / 8);

    // QKV projection -> head-blocked qkv (128x64 tiles, 2-deep pipeline)
    gemm_bt<1, 0, 0, 1><<<dim3(QKV_DIM / 64, M / 128), 256, 0, stream>>>(
        xb, wqkvb, b_in, qkvb, M, QKV_DIM, C_DIM);

    // fused windowed attention (head-blocked in/out), 8 waves/block
    attn_kernel<<<nWin * NHEAD, 512, 0, stream>>>(qkvb, attb, M);

    // output projection: A head-blocked bf16, fp32 dense out (2-deep pipeline)
    gemm_bt<0, 1, 1, 0><<<dim3(C_DIM / 64, M / 128), 256, 0, stream>>>(
        attb, woutb, nullptr, d_out, M, C_DIM, C_DIM);
}

// Round 24
// 117.505 us; speedup vs baseline: 1.1264x; 1.1264x over previous
//
#include <hip/hip_runtime.h>
#include <hip/hip_bf16.h>

typedef __attribute__((ext_vector_type(4)))  float  f32x4;
typedef __attribute__((ext_vector_type(16))) float  f32x16;
typedef __attribute__((ext_vector_type(8)))  short  bf16x8;
typedef __attribute__((ext_vector_type(8)))  ushort u16x8;

#define C_DIM   384
#define QKV_DIM 1152
#define NHEAD   12
#define HDIM    32
#define NTOK    256

__device__ __forceinline__ ushort f2bf(float f) {
    union { __hip_bfloat16 h; ushort u; } cv;
    cv.h = __float2bfloat16(f);
    return cv.u;
}

// ---------------- fp32 -> bf16 convert (grid-strided, 8 elems/iter) ----------------
__global__ void cvt_kernel(const float* __restrict__ in, ushort* __restrict__ out, int n8) {
    const int stride = gridDim.x * blockDim.x;
    for (int i = blockIdx.x * blockDim.x + threadIdx.x; i < n8; i += stride) {
        const float4 v0 = reinterpret_cast<const float4*>(in)[2 * i];
        const float4 v1 = reinterpret_cast<const float4*>(in)[2 * i + 1];
        union { ushort u[8]; u16x8 v; } o;
        o.u[0] = f2bf(v0.x); o.u[1] = f2bf(v0.y);
        o.u[2] = f2bf(v0.z); o.u[3] = f2bf(v0.w);
        o.u[4] = f2bf(v1.x); o.u[5] = f2bf(v1.y);
        o.u[6] = f2bf(v1.z); o.u[7] = f2bf(v1.w);
        reinterpret_cast<u16x8*>(out)[i] = o.v;
    }
}

// ---------------- GEMM A: 128x128 tile (r17-verbatim) — used for QKV ----------------
// 4 waves (64x64, acc[4][4]), counted-vmcnt(8), T1 XCD-bijective remap.
template<int BIAS, int OUTF32, int AHB, int OHB>
__global__ __launch_bounds__(256, 2) void gemm_bt_w(const ushort* __restrict__ A,
                                                    const ushort* __restrict__ Bw,
                                                    const float* __restrict__ bias,
                                                    void* __restrict__ Cout,
                                                    int M, int N, int K) {
    __shared__ __align__(16) ushort As[2][128 * 64];
    __shared__ __align__(16) ushort Bs[2][128 * 64];

    const int t    = threadIdx.x;
    const int lane = t & 63;
    const int wave = t >> 6;
    const int wr   = (wave >> 1) * 64;
    const int wc   = (wave & 1) * 64;
    const int lr   = lane & 15;
    const int lg   = lane >> 4;

    const int gx  = gridDim.x;
    const int nwg = gx * gridDim.y;
    const int hw  = blockIdx.y * gx + blockIdx.x;
    const int cpx = nwg >> 3;
    const int lin = (hw & 7) * cpx + (hw >> 3);
    const int by  = lin / gx;
    const int bx  = lin - by * gx;
    const int mBase = by * 128;
    const int nBase = bx * 128;

    f32x4 acc[4][4] = {};
    const int nK = K >> 6;

    auto stage = [&](int kt, int c) {               // 8 global_load_lds / thread
        const int k0 = kt << 6;
#pragma unroll
        for (int it = 0; it < 4; ++it) {            // A: 128 rows x 64 k
            const int idx = it * 256 + t;
            const int r   = idx >> 3;
            const int cb  = (idx & 7) ^ (r & 7);
            const ushort* ga;
            if (AHB) {
                const int k = k0 + cb * 8;
                ga = A + ((size_t)(k >> 5) * M + (mBase + r)) * 32 + (k & 31);
            } else {
                ga = A + (size_t)(mBase + r) * K + k0 + cb * 8;
            }
            __builtin_amdgcn_global_load_lds(
                (const __attribute__((address_space(1))) void*)ga,
                (__attribute__((address_space(3))) void*)(&As[c][it * 2048 + wave * 512]),
                16, 0, 0);
        }
#pragma unroll
        for (int it = 0; it < 4; ++it) {            // B: 128 rows x 64 k
            const int idx = it * 256 + t;
            const int r   = idx >> 3;
            const int cb  = (idx & 7) ^ (r & 7);
            const ushort* gb = Bw + (size_t)(nBase + r) * K + k0 + cb * 8;
            __builtin_amdgcn_global_load_lds(
                (const __attribute__((address_space(1))) void*)gb,
                (__attribute__((address_space(3))) void*)(&Bs[c][it * 2048 + wave * 512]),
                16, 0, 0);
        }
    };

    stage(0, 0);
    int cur = 0;

    for (int kt = 0; kt < nK; ++kt) {
        if (kt + 1 < nK) {
            stage(kt + 1, cur ^ 1);                 // 8 more loads in flight
            asm volatile("s_waitcnt vmcnt(8)" ::: "memory");
        } else {
            asm volatile("s_waitcnt vmcnt(0)" ::: "memory");
        }
        __builtin_amdgcn_s_barrier();
        __builtin_amdgcn_sched_barrier(0);

#pragma unroll
        for (int kk = 0; kk < 2; ++kk) {
            bf16x8 af[4], bfr[4];
#pragma unroll
            for (int m = 0; m < 4; ++m) {
                const int r = wr + m * 16 + lr;
                af[m] = *reinterpret_cast<const bf16x8*>(
                    &As[cur][r * 64 + (((kk * 4 + lg) ^ (r & 7)) << 3)]);
            }
#pragma unroll
            for (int n = 0; n < 4; ++n) {
                const int r = wc + n * 16 + lr;
                bfr[n] = *reinterpret_cast<const bf16x8*>(
                    &Bs[cur][r * 64 + (((kk * 4 + lg) ^ (r & 7)) << 3)]);
            }
#pragma unroll
            for (int m = 0; m < 4; ++m)
#pragma unroll
                for (int n = 0; n < 4; ++n)
                    acc[m][n] = __builtin_amdgcn_mfma_f32_16x16x32_bf16(af[m], bfr[n], acc[m][n], 0, 0, 0);
        }

        __builtin_amdgcn_sched_barrier(0);
        __builtin_amdgcn_s_barrier();
        cur ^= 1;
    }

#pragma unroll
    for (int n = 0; n < 4; ++n) {
        const int col = nBase + wc + n * 16 + lr;
        const float bv = BIAS ? bias[col] : 0.f;
        const int sel  = OHB ? (col / 384) : 0;
        const int c384 = OHB ? (col - sel * 384) : 0;
#pragma unroll
        for (int m = 0; m < 4; ++m) {
            const int row0 = mBase + wr + m * 16 + lg * 4;
#pragma unroll
            for (int j = 0; j < 4; ++j) {
                const float v = acc[m][n][j] + bv;
                const int row = row0 + j;
                if (OUTF32) {
                    reinterpret_cast<float*>(Cout)[(size_t)row * N + col] = v;
                } else if (OHB) {
                    reinterpret_cast<ushort*>(Cout)[
                        ((size_t)(sel * NHEAD + (c384 >> 5)) * M + row) * 32 + (c384 & 31)] = f2bf(v);
                } else {
                    reinterpret_cast<ushort*>(Cout)[(size_t)row * N + col] = f2bf(v);
                }
            }
        }
    }
}

// ---------------- GEMM B: 128x64 tile (r13/r16-verbatim) — used for out-proj ----------------
// 4 waves (64x32, acc[4][2]), counted-vmcnt(6), T1 XCD-bijective remap.
template<int BIAS, int OUTF32, int AHB, int OHB>
__global__ __launch_bounds__(256, 3) void gemm_bt(const ushort* __restrict__ A,
                                                  const ushort* __restrict__ Bw,
                                                  const float* __restrict__ bias,
                                                  void* __restrict__ Cout,
                                                  int M, int N, int K) {
    __shared__ __align__(16) ushort As[2][128 * 64];
    __shared__ __align__(16) ushort Bs[2][64 * 64];

    const int t    = threadIdx.x;
    const int lane = t & 63;
    const int wave = t >> 6;
    const int wr   = (wave >> 1) * 64;
    const int wc   = (wave & 1) * 32;
    const int lr   = lane & 15;
    const int lg   = lane >> 4;

    const int gx  = gridDim.x;
    const int nwg = gx * gridDim.y;
    const int hw  = blockIdx.y * gx + blockIdx.x;
    const int cpx = nwg >> 3;
    const int lin = (hw & 7) * cpx + (hw >> 3);
    const int by  = lin / gx;
    const int bx  = lin - by * gx;
    const int mBase = by * 128;
    const int nBase = bx * 64;

    f32x4 acc[4][2] = {};
    const int nK = K >> 6;

    auto stage = [&](int kt, int c) {               // 6 global_load_lds / thread
        const int k0 = kt << 6;
#pragma unroll
        for (int it = 0; it < 4; ++it) {            // A: 128 rows x 64 k
            const int idx = it * 256 + t;
            const int r   = idx >> 3;
            const int cb  = (idx & 7) ^ (r & 7);
            const ushort* ga;
            if (AHB) {
                const int k = k0 + cb * 8;
                ga = A + ((size_t)(k >> 5) * M + (mBase + r)) * 32 + (k & 31);
            } else {
                ga = A + (size_t)(mBase + r) * K + k0 + cb * 8;
            }
            __builtin_amdgcn_global_load_lds(
                (const __attribute__((address_space(1))) void*)ga,
                (__attribute__((address_space(3))) void*)(&As[c][it * 2048 + wave * 512]),
                16, 0, 0);
        }
#pragma unroll
        for (int it = 0; it < 2; ++it) {            // B: 64 rows x 64 k
            const int idx = it * 256 + t;
            const int r   = idx >> 3;
            const int cb  = (idx & 7) ^ (r & 7);
            const ushort* gb = Bw + (size_t)(nBase + r) * K + k0 + cb * 8;
            __builtin_amdgcn_global_load_lds(
                (const __attribute__((address_space(1))) void*)gb,
                (__attribute__((address_space(3))) void*)(&Bs[c][it * 2048 + wave * 512]),
                16, 0, 0);
        }
    };

    stage(0, 0);
    int cur = 0;

    for (int kt = 0; kt < nK; ++kt) {
        if (kt + 1 < nK) {
            stage(kt + 1, cur ^ 1);                 // 6 more loads in flight
            asm volatile("s_waitcnt vmcnt(6)" ::: "memory");
        } else {
            asm volatile("s_waitcnt vmcnt(0)" ::: "memory");
        }
        __builtin_amdgcn_s_barrier();
        __builtin_amdgcn_sched_barrier(0);

#pragma unroll
        for (int kk = 0; kk < 2; ++kk) {
            bf16x8 af[4], bfr[2];
#pragma unroll
            for (int m = 0; m < 4; ++m) {
                const int r = wr + m * 16 + lr;
                af[m] = *reinterpret_cast<const bf16x8*>(
                    &As[cur][r * 64 + (((kk * 4 + lg) ^ (r & 7)) << 3)]);
            }
#pragma unroll
            for (int n = 0; n < 2; ++n) {
                const int r = wc + n * 16 + lr;
                bfr[n] = *reinterpret_cast<const bf16x8*>(
                    &Bs[cur][r * 64 + (((kk * 4 + lg) ^ (r & 7)) << 3)]);
            }
#pragma unroll
            for (int m = 0; m < 4; ++m)
#pragma unroll
                for (int n = 0; n < 2; ++n)
                    acc[m][n] = __builtin_amdgcn_mfma_f32_16x16x32_bf16(af[m], bfr[n], acc[m][n], 0, 0, 0);
        }

        __builtin_amdgcn_sched_barrier(0);
        __builtin_amdgcn_s_barrier();
        cur ^= 1;
    }

#pragma unroll
    for (int n = 0; n < 2; ++n) {
        const int col = nBase + wc + n * 16 + lr;
        const float bv = BIAS ? bias[col] : 0.f;
        const int sel  = OHB ? (col / 384) : 0;
        const int c384 = OHB ? (col - sel * 384) : 0;
#pragma unroll
        for (int m = 0; m < 4; ++m) {
            const int row0 = mBase + wr + m * 16 + lg * 4;
#pragma unroll
            for (int j = 0; j < 4; ++j) {
                const float v = acc[m][n][j] + bv;
                const int row = row0 + j;
                if (OUTF32) {
                    reinterpret_cast<float*>(Cout)[(size_t)row * N + col] = v;
                } else if (OHB) {
                    reinterpret_cast<ushort*>(Cout)[
                        ((size_t)(sel * NHEAD + (c384 >> 5)) * M + row) * 32 + (c384 & 31)] = f2bf(v);
                } else {
                    reinterpret_cast<ushort*>(Cout)[(size_t)row * N + col] = f2bf(v);
                }
            }
        }
    }
}

// ---------------- fused attention: one block per (window, head) ----------------
// r13-VERBATIM (8 waves x 512 threads, one 32-row chunk per wave; two-pass
// recompute, normalized-P single bf16 rounding).
__global__ __launch_bounds__(512) void attn_kernel(const ushort* __restrict__ qkv,
                                                   ushort* __restrict__ att,
                                                   int Mtok) {
    __shared__ __align__(16) ushort Ks[NTOK * HDIM];   // [key][d], swizzled 16B blocks
    __shared__ __align__(16) ushort Vt[HDIM * NTOK];   // [d][key], swizzled 16B blocks

    const int bid = blockIdx.x;
    const int win = bid / NHEAD;
    const int h   = bid % NHEAD;

    const int t    = threadIdx.x;
    const int lane = t & 63;
    const int wave = t >> 6;          // 0..7
    const int l31  = lane & 31;
    const int h5   = lane >> 5;

    const size_t winRow = (size_t)win * NTOK;
    const ushort* Qbase = qkv + ((size_t)h * Mtok + winRow) * HDIM;
    const ushort* Kbase = qkv + ((size_t)(NHEAD + h) * Mtok + winRow) * HDIM;
    const ushort* Vbase = qkv + ((size_t)(2 * NHEAD + h) * Mtok + winRow) * HDIM;

#pragma unroll
    for (int it = 0; it < 2; ++it) {
        const int idx = it * 512 + t;
        const int key = idx >> 2;
        const int cb  = (idx & 3) ^ (key & 3);
        const ushort* gk = Kbase + key * HDIM + cb * 8;
        __builtin_amdgcn_global_load_lds(
            (const __attribute__((address_space(1))) void*)gk,
            (__attribute__((address_space(3))) void*)(&Ks[it * 4096 + wave * 512]),
            16, 0, 0);
    }
#pragma unroll
    for (int it = 0; it < 2; ++it) {
        const int idx = it * 512 + t;
        const int key = idx >> 2;
        const int cb  = idx & 3;
        u16x8 v8 = *reinterpret_cast<const u16x8*>(Vbase + key * HDIM + cb * 8);
#pragma unroll
        for (int jj = 0; jj < 8; ++jj) {
            const int dd  = cb * 8 + jj;
            const int blk = (key >> 3) ^ (dd & 7) ^ ((2 * (dd >> 3)) & 6);
            Vt[dd * NTOK + blk * 8 + (key & 7)] = v8[jj];
        }
    }
    __syncthreads();

    const float c1   = 0.25503509f;                 // 32^-0.5 * log2(e)
    const int   vmsk = (l31 & 7) ^ ((2 * (l31 >> 3)) & 6);
    const int   kmsk = l31 & 3;
    const int   q0   = wave * 32;                   // one 32-row chunk per wave

    const int qrow = q0 + l31;
    const bf16x8 qf0 = *reinterpret_cast<const bf16x8*>(
        Qbase + (size_t)qrow * HDIM + h5 * 8);
    const bf16x8 qf1 = *reinterpret_cast<const bf16x8*>(
        Qbase + (size_t)qrow * HDIM + 16 + h5 * 8);

    // ---- pass 1: softmax denominator (score tile dies each iteration) ----
    float sm0 = 0.f, sm1 = 0.f, sm2 = 0.f, sm3 = 0.f;
#pragma unroll
    for (int tt = 0; tt < 8; ++tt) {
        const int key = tt * 32 + l31;
        const bf16x8 kf0 = *reinterpret_cast<const bf16x8*>(
            &Ks[key * HDIM + ((h5 ^ kmsk) << 3)]);
        const bf16x8 kf1 = *reinterpret_cast<const bf16x8*>(
            &Ks[key * HDIM + (((2 + h5) ^ kmsk) << 3)]);
        f32x16 s = {};
        s = __builtin_amdgcn_mfma_f32_32x32x16_bf16(kf0, qf0, s, 0, 0, 0);
        s = __builtin_amdgcn_mfma_f32_32x32x16_bf16(kf1, qf1, s, 0, 0, 0);
#pragma unroll
        for (int r = 0; r < 16; r += 4) {
            sm0 += __builtin_amdgcn_exp2f(s[r + 0] * c1);
            sm1 += __builtin_amdgcn_exp2f(s[r + 1] * c1);
            sm2 += __builtin_amdgcn_exp2f(s[r + 2] * c1);
            sm3 += __builtin_amdgcn_exp2f(s[r + 3] * c1);
        }
    }
    float sm = (sm0 + sm1) + (sm2 + sm3);
    sm += __shfl_xor(sm, 32, 64);
    const float inv = __builtin_amdgcn_rcpf(sm);

    // ---- pass 2: recompute QK, pack NORMALIZED P (fp32->bf16 once), PV ----
    f32x16 O = {};
#pragma unroll
    for (int tt = 0; tt < 8; ++tt) {
        const int key = tt * 32 + l31;
        const bf16x8 kf0 = *reinterpret_cast<const bf16x8*>(
            &Ks[key * HDIM + ((h5 ^ kmsk) << 3)]);
        const bf16x8 kf1 = *reinterpret_cast<const bf16x8*>(
            &Ks[key * HDIM + (((2 + h5) ^ kmsk) << 3)]);
        f32x16 s = {};
        s = __builtin_amdgcn_mfma_f32_32x32x16_bf16(kf0, qf0, s, 0, 0, 0);
        s = __builtin_amdgcn_mfma_f32_32x32x16_bf16(kf1, qf1, s, 0, 0, 0);

        uint pk8[8];
#pragma unroll
        for (int m = 0; m < 8; ++m) {
            const int r = 4 * (m >> 1) + 2 * (m & 1);
            const float lo = __builtin_amdgcn_exp2f(s[r + 0] * c1) * inv;
            const float hi = __builtin_amdgcn_exp2f(s[r + 1] * c1) * inv;
            uint d;
            asm("v_cvt_pk_bf16_f32 %0, %1, %2" : "=v"(d) : "v"(lo), "v"(hi));
            pk8[m] = d;
        }

        // PV: half of the P-fragment comes from partner lane^32 (r11-verbatim)
#pragma unroll
        for (int k16 = 0; k16 < 2; ++k16) {
            const int mb = 4 * k16;
            const uint s0 = h5 ? pk8[mb + 0] : pk8[mb + 2];
            const uint s1 = h5 ? pk8[mb + 1] : pk8[mb + 3];
            const uint x0 = (uint)__shfl_xor((int)s0, 32, 64);
            const uint x1 = (uint)__shfl_xor((int)s1, 32, 64);
            union { uint u[4]; bf16x8 v; } pw;
            pw.u[0] = h5 ? x0 : pk8[mb + 0];
            pw.u[1] = h5 ? x1 : pk8[mb + 1];
            pw.u[2] = h5 ? pk8[mb + 2] : x0;
            pw.u[3] = h5 ? pk8[mb + 3] : x1;
            const int blk = (4 * tt + 2 * k16 + h5) ^ vmsk;
            const bf16x8 vf = *reinterpret_cast<const bf16x8*>(
                &Vt[l31 * NTOK + blk * 8]);
            O = __builtin_amdgcn_mfma_f32_32x32x16_bf16(pw.v, vf, O, 0, 0, 0);
        }
    }

    // ---- store (r3-verbatim): row=(r&3)+8(r>>2)+4h5, col d=l31 ----
    ushort* obase = att + ((size_t)h * Mtok + winRow + q0) * HDIM + l31;
#pragma unroll
    for (int r = 0; r < 16; ++r) {
        const int qr = (r & 3) + 8 * (r >> 2) + 4 * h5;
        obase[(size_t)qr * HDIM] = f2bf(O[r]);
    }
}

// ---------------- host ----------------
extern "C" void kernel_launch(void* const* d_in, const int* in_sizes, int n_in,
                              void* d_out, int out_size, void* d_ws, size_t ws_size,
                              hipStream_t stream) {
    const float* x     = (const float*)d_in[0];
    const float* w_in  = (const float*)d_in[1];
    const float* b_in  = (const float*)d_in[2];
    const float* w_out = (const float*)d_in[3];

    const int M    = in_sizes[0] / C_DIM;  // 32768 tokens
    const int nWin = M / NTOK;             // 128 windows

    char* ws = (char*)d_ws;
    size_t off = 0;
    ushort* xb    = (ushort*)(ws + off); off += (size_t)M * C_DIM * 2;
    ushort* qkvb  = (ushort*)(ws + off); off += (size_t)M * QKV_DIM * 2;   // [36][M][32]
    ushort* attb  = (ushort*)(ws + off); off += (size_t)M * C_DIM * 2;     // [12][M][32]
    ushort* wqkvb = (ushort*)(ws + off); off += (size_t)QKV_DIM * C_DIM * 2;
    ushort* woutb = (ushort*)(ws + off);

    // grid-strided converts (8 elems/thread-iter, 16B stores)
    cvt_kernel<<<2048, 256, 0, stream>>>(x, xb, M * C_DIM / 8);
    cvt_kernel<<<(QKV_DIM * C_DIM / 8 + 255) / 256, 256, 0, stream>>>(
        w_in, wqkvb, QKV_DIM * C_DIM / 8);
    cvt_kernel<<<(C_DIM * C_DIM / 8 + 255) / 256, 256, 0, stream>>>(
        w_out, woutb, C_DIM * C_DIM / 8);

    // QKV projection -> head-blocked qkv (128x128 tiles, measured faster for this shape)
    gemm_bt_w<1, 0, 0, 1><<<dim3(QKV_DIM / 128, M / 128), 256, 0, stream>>>(
        xb, wqkvb, b_in, qkvb, M, QKV_DIM, C_DIM);

    // fused windowed attention (head-blocked in/out), 8 waves/block
    attn_kernel<<<nWin * NHEAD, 512, 0, stream>>>(qkvb, attb, M);

    // output projection: A head-blocked bf16, fp32 dense out (128x64 tiles,
    // measured faster for N=384's small grid)
    gemm_bt<0, 1, 1, 0><<<dim3(C_DIM / 64, M / 128), 256, 0, stream>>>(
        attb, woutb, nullptr, d_out, M, C_DIM, C_DIM);
}

// Round 25
// 114.292 us; speedup vs baseline: 1.1580x; 1.0281x over previous
//
#include <hip/hip_runtime.h>
#include <hip/hip_bf16.h>

typedef __attribute__((ext_vector_type(4)))  float  f32x4;
typedef __attribute__((ext_vector_type(16))) float  f32x16;
typedef __attribute__((ext_vector_type(8)))  short  bf16x8;
typedef __attribute__((ext_vector_type(8)))  ushort u16x8;

#define C_DIM   384
#define QKV_DIM 1152
#define NHEAD   12
#define HDIM    32
#define NTOK    256

__device__ __forceinline__ ushort f2bf(float f) {
    union { __hip_bfloat16 h; ushort u; } cv;
    cv.h = __float2bfloat16(f);
    return cv.u;
}

// ------- fused fp32 -> bf16 convert for THREE tensors (grid-strided) -------
// Segments: [0,n0): x -> xb ; [n0,n0+n1): w_in -> wqkvb ; [n0+n1,n0+n1+n2).
// Same per-element RNE convert and vector widths as the split kernels ->
// bit-identical buffer images; saves 2 kernel launches.
__global__ void cvt3_kernel(const float* __restrict__ s0, ushort* __restrict__ d0, int n0,
                            const float* __restrict__ s1, ushort* __restrict__ d1, int n1,
                            const float* __restrict__ s2, ushort* __restrict__ d2, int n2) {
    const int stride = gridDim.x * blockDim.x;
    const int ntot = n0 + n1 + n2;
    for (int i = blockIdx.x * blockDim.x + threadIdx.x; i < ntot; i += stride) {
        const float* src; ushort* dst; int j;
        if (i < n0)           { src = s0; dst = d0; j = i; }
        else if (i < n0 + n1) { src = s1; dst = d1; j = i - n0; }
        else                  { src = s2; dst = d2; j = i - n0 - n1; }
        const float4 v0 = reinterpret_cast<const float4*>(src)[2 * j];
        const float4 v1 = reinterpret_cast<const float4*>(src)[2 * j + 1];
        union { ushort u[8]; u16x8 v; } o;
        o.u[0] = f2bf(v0.x); o.u[1] = f2bf(v0.y);
        o.u[2] = f2bf(v0.z); o.u[3] = f2bf(v0.w);
        o.u[4] = f2bf(v1.x); o.u[5] = f2bf(v1.y);
        o.u[6] = f2bf(v1.z); o.u[7] = f2bf(v1.w);
        reinterpret_cast<u16x8*>(dst)[j] = o.v;
    }
}

// ---------------- GEMM A: 128x128 tile (r17-verbatim) — used for QKV ----------------
// 4 waves (64x64, acc[4][4]), counted-vmcnt(8), T1 XCD-bijective remap.
template<int BIAS, int OUTF32, int AHB, int OHB>
__global__ __launch_bounds__(256, 2) void gemm_bt_w(const ushort* __restrict__ A,
                                                    const ushort* __restrict__ Bw,
                                                    const float* __restrict__ bias,
                                                    void* __restrict__ Cout,
                                                    int M, int N, int K) {
    __shared__ __align__(16) ushort As[2][128 * 64];
    __shared__ __align__(16) ushort Bs[2][128 * 64];

    const int t    = threadIdx.x;
    const int lane = t & 63;
    const int wave = t >> 6;
    const int wr   = (wave >> 1) * 64;
    const int wc   = (wave & 1) * 64;
    const int lr   = lane & 15;
    const int lg   = lane >> 4;

    const int gx  = gridDim.x;
    const int nwg = gx * gridDim.y;
    const int hw  = blockIdx.y * gx + blockIdx.x;
    const int cpx = nwg >> 3;
    const int lin = (hw & 7) * cpx + (hw >> 3);
    const int by  = lin / gx;
    const int bx  = lin - by * gx;
    const int mBase = by * 128;
    const int nBase = bx * 128;

    f32x4 acc[4][4] = {};
    const int nK = K >> 6;

    auto stage = [&](int kt, int c) {               // 8 global_load_lds / thread
        const int k0 = kt << 6;
#pragma unroll
        for (int it = 0; it < 4; ++it) {            // A: 128 rows x 64 k
            const int idx = it * 256 + t;
            const int r   = idx >> 3;
            const int cb  = (idx & 7) ^ (r & 7);
            const ushort* ga;
            if (AHB) {
                const int k = k0 + cb * 8;
                ga = A + ((size_t)(k >> 5) * M + (mBase + r)) * 32 + (k & 31);
            } else {
                ga = A + (size_t)(mBase + r) * K + k0 + cb * 8;
            }
            __builtin_amdgcn_global_load_lds(
                (const __attribute__((address_space(1))) void*)ga,
                (__attribute__((address_space(3))) void*)(&As[c][it * 2048 + wave * 512]),
                16, 0, 0);
        }
#pragma unroll
        for (int it = 0; it < 4; ++it) {            // B: 128 rows x 64 k
            const int idx = it * 256 + t;
            const int r   = idx >> 3;
            const int cb  = (idx & 7) ^ (r & 7);
            const ushort* gb = Bw + (size_t)(nBase + r) * K + k0 + cb * 8;
            __builtin_amdgcn_global_load_lds(
                (const __attribute__((address_space(1))) void*)gb,
                (__attribute__((address_space(3))) void*)(&Bs[c][it * 2048 + wave * 512]),
                16, 0, 0);
        }
    };

    stage(0, 0);
    int cur = 0;

    for (int kt = 0; kt < nK; ++kt) {
        if (kt + 1 < nK) {
            stage(kt + 1, cur ^ 1);                 // 8 more loads in flight
            asm volatile("s_waitcnt vmcnt(8)" ::: "memory");
        } else {
            asm volatile("s_waitcnt vmcnt(0)" ::: "memory");
        }
        __builtin_amdgcn_s_barrier();
        __builtin_amdgcn_sched_barrier(0);

#pragma unroll
        for (int kk = 0; kk < 2; ++kk) {
            bf16x8 af[4], bfr[4];
#pragma unroll
            for (int m = 0; m < 4; ++m) {
                const int r = wr + m * 16 + lr;
                af[m] = *reinterpret_cast<const bf16x8*>(
                    &As[cur][r * 64 + (((kk * 4 + lg) ^ (r & 7)) << 3)]);
            }
#pragma unroll
            for (int n = 0; n < 4; ++n) {
                const int r = wc + n * 16 + lr;
                bfr[n] = *reinterpret_cast<const bf16x8*>(
                    &Bs[cur][r * 64 + (((kk * 4 + lg) ^ (r & 7)) << 3)]);
            }
#pragma unroll
            for (int m = 0; m < 4; ++m)
#pragma unroll
                for (int n = 0; n < 4; ++n)
                    acc[m][n] = __builtin_amdgcn_mfma_f32_16x16x32_bf16(af[m], bfr[n], acc[m][n], 0, 0, 0);
        }

        __builtin_amdgcn_sched_barrier(0);
        __builtin_amdgcn_s_barrier();
        cur ^= 1;
    }

#pragma unroll
    for (int n = 0; n < 4; ++n) {
        const int col = nBase + wc + n * 16 + lr;
        const float bv = BIAS ? bias[col] : 0.f;
        const int sel  = OHB ? (col / 384) : 0;
        const int c384 = OHB ? (col - sel * 384) : 0;
#pragma unroll
        for (int m = 0; m < 4; ++m) {
            const int row0 = mBase + wr + m * 16 + lg * 4;
#pragma unroll
            for (int j = 0; j < 4; ++j) {
                const float v = acc[m][n][j] + bv;
                const int row = row0 + j;
                if (OUTF32) {
                    reinterpret_cast<float*>(Cout)[(size_t)row * N + col] = v;
                } else if (OHB) {
                    reinterpret_cast<ushort*>(Cout)[
                        ((size_t)(sel * NHEAD + (c384 >> 5)) * M + row) * 32 + (c384 & 31)] = f2bf(v);
                } else {
                    reinterpret_cast<ushort*>(Cout)[(size_t)row * N + col] = f2bf(v);
                }
            }
        }
    }
}

// ---------------- GEMM B: 128x64 tile (r13/r16-verbatim) — used for out-proj ----------------
// 4 waves (64x32, acc[4][2]), counted-vmcnt(6), T1 XCD-bijective remap.
template<int BIAS, int OUTF32, int AHB, int OHB>
__global__ __launch_bounds__(256, 3) void gemm_bt(const ushort* __restrict__ A,
                                                  const ushort* __restrict__ Bw,
                                                  const float* __restrict__ bias,
                                                  void* __restrict__ Cout,
                                                  int M, int N, int K) {
    __shared__ __align__(16) ushort As[2][128 * 64];
    __shared__ __align__(16) ushort Bs[2][64 * 64];

    const int t    = threadIdx.x;
    const int lane = t & 63;
    const int wave = t >> 6;
    const int wr   = (wave >> 1) * 64;
    const int wc   = (wave & 1) * 32;
    const int lr   = lane & 15;
    const int lg   = lane >> 4;

    const int gx  = gridDim.x;
    const int nwg = gx * gridDim.y;
    const int hw  = blockIdx.y * gx + blockIdx.x;
    const int cpx = nwg >> 3;
    const int lin = (hw & 7) * cpx + (hw >> 3);
    const int by  = lin / gx;
    const int bx  = lin - by * gx;
    const int mBase = by * 128;
    const int nBase = bx * 64;

    f32x4 acc[4][2] = {};
    const int nK = K >> 6;

    auto stage = [&](int kt, int c) {               // 6 global_load_lds / thread
        const int k0 = kt << 6;
#pragma unroll
        for (int it = 0; it < 4; ++it) {            // A: 128 rows x 64 k
            const int idx = it * 256 + t;
            const int r   = idx >> 3;
            const int cb  = (idx & 7) ^ (r & 7);
            const ushort* ga;
            if (AHB) {
                const int k = k0 + cb * 8;
                ga = A + ((size_t)(k >> 5) * M + (mBase + r)) * 32 + (k & 31);
            } else {
                ga = A + (size_t)(mBase + r) * K + k0 + cb * 8;
            }
            __builtin_amdgcn_global_load_lds(
                (const __attribute__((address_space(1))) void*)ga,
                (__attribute__((address_space(3))) void*)(&As[c][it * 2048 + wave * 512]),
                16, 0, 0);
        }
#pragma unroll
        for (int it = 0; it < 2; ++it) {            // B: 64 rows x 64 k
            const int idx = it * 256 + t;
            const int r   = idx >> 3;
            const int cb  = (idx & 7) ^ (r & 7);
            const ushort* gb = Bw + (size_t)(nBase + r) * K + k0 + cb * 8;
            __builtin_amdgcn_global_load_lds(
                (const __attribute__((address_space(1))) void*)gb,
                (__attribute__((address_space(3))) void*)(&Bs[c][it * 2048 + wave * 512]),
                16, 0, 0);
        }
    };

    stage(0, 0);
    int cur = 0;

    for (int kt = 0; kt < nK; ++kt) {
        if (kt + 1 < nK) {
            stage(kt + 1, cur ^ 1);                 // 6 more loads in flight
            asm volatile("s_waitcnt vmcnt(6)" ::: "memory");
        } else {
            asm volatile("s_waitcnt vmcnt(0)" ::: "memory");
        }
        __builtin_amdgcn_s_barrier();
        __builtin_amdgcn_sched_barrier(0);

#pragma unroll
        for (int kk = 0; kk < 2; ++kk) {
            bf16x8 af[4], bfr[2];
#pragma unroll
            for (int m = 0; m < 4; ++m) {
                const int r = wr + m * 16 + lr;
                af[m] = *reinterpret_cast<const bf16x8*>(
                    &As[cur][r * 64 + (((kk * 4 + lg) ^ (r & 7)) << 3)]);
            }
#pragma unroll
            for (int n = 0; n < 2; ++n) {
                const int r = wc + n * 16 + lr;
                bfr[n] = *reinterpret_cast<const bf16x8*>(
                    &Bs[cur][r * 64 + (((kk * 4 + lg) ^ (r & 7)) << 3)]);
            }
#pragma unroll
            for (int m = 0; m < 4; ++m)
#pragma unroll
                for (int n = 0; n < 2; ++n)
                    acc[m][n] = __builtin_amdgcn_mfma_f32_16x16x32_bf16(af[m], bfr[n], acc[m][n], 0, 0, 0);
        }

        __builtin_amdgcn_sched_barrier(0);
        __builtin_amdgcn_s_barrier();
        cur ^= 1;
    }

#pragma unroll
    for (int n = 0; n < 2; ++n) {
        const int col = nBase + wc + n * 16 + lr;
        const float bv = BIAS ? bias[col] : 0.f;
        const int sel  = OHB ? (col / 384) : 0;
        const int c384 = OHB ? (col - sel * 384) : 0;
#pragma unroll
        for (int m = 0; m < 4; ++m) {
            const int row0 = mBase + wr + m * 16 + lg * 4;
#pragma unroll
            for (int j = 0; j < 4; ++j) {
                const float v = acc[m][n][j] + bv;
                const int row = row0 + j;
                if (OUTF32) {
                    reinterpret_cast<float*>(Cout)[(size_t)row * N + col] = v;
                } else if (OHB) {
                    reinterpret_cast<ushort*>(Cout)[
                        ((size_t)(sel * NHEAD + (c384 >> 5)) * M + row) * 32 + (c384 & 31)] = f2bf(v);
                } else {
                    reinterpret_cast<ushort*>(Cout)[(size_t)row * N + col] = f2bf(v);
                }
            }
        }
    }
}

// ---------------- fused attention: one block per (window, head) ----------------
// r13-VERBATIM (8 waves x 512 threads, one 32-row chunk per wave; two-pass
// recompute, normalized-P single bf16 rounding).
__global__ __launch_bounds__(512) void attn_kernel(const ushort* __restrict__ qkv,
                                                   ushort* __restrict__ att,
                                                   int Mtok) {
    __shared__ __align__(16) ushort Ks[NTOK * HDIM];   // [key][d], swizzled 16B blocks
    __shared__ __align__(16) ushort Vt[HDIM * NTOK];   // [d][key], swizzled 16B blocks

    const int bid = blockIdx.x;
    const int win = bid / NHEAD;
    const int h   = bid % NHEAD;

    const int t    = threadIdx.x;
    const int lane = t & 63;
    const int wave = t >> 6;          // 0..7
    const int l31  = lane & 31;
    const int h5   = lane >> 5;

    const size_t winRow = (size_t)win * NTOK;
    const ushort* Qbase = qkv + ((size_t)h * Mtok + winRow) * HDIM;
    const ushort* Kbase = qkv + ((size_t)(NHEAD + h) * Mtok + winRow) * HDIM;
    const ushort* Vbase = qkv + ((size_t)(2 * NHEAD + h) * Mtok + winRow) * HDIM;

#pragma unroll
    for (int it = 0; it < 2; ++it) {
        const int idx = it * 512 + t;
        const int key = idx >> 2;
        const int cb  = (idx & 3) ^ (key & 3);
        const ushort* gk = Kbase + key * HDIM + cb * 8;
        __builtin_amdgcn_global_load_lds(
            (const __attribute__((address_space(1))) void*)gk,
            (__attribute__((address_space(3))) void*)(&Ks[it * 4096 + wave * 512]),
            16, 0, 0);
    }
#pragma unroll
    for (int it = 0; it < 2; ++it) {
        const int idx = it * 512 + t;
        const int key = idx >> 2;
        const int cb  = idx & 3;
        u16x8 v8 = *reinterpret_cast<const u16x8*>(Vbase + key * HDIM + cb * 8);
#pragma unroll
        for (int jj = 0; jj < 8; ++jj) {
            const int dd  = cb * 8 + jj;
            const int blk = (key >> 3) ^ (dd & 7) ^ ((2 * (dd >> 3)) & 6);
            Vt[dd * NTOK + blk * 8 + (key & 7)] = v8[jj];
        }
    }
    __syncthreads();

    const float c1   = 0.25503509f;                 // 32^-0.5 * log2(e)
    const int   vmsk = (l31 & 7) ^ ((2 * (l31 >> 3)) & 6);
    const int   kmsk = l31 & 3;
    const int   q0   = wave * 32;                   // one 32-row chunk per wave

    const int qrow = q0 + l31;
    const bf16x8 qf0 = *reinterpret_cast<const bf16x8*>(
        Qbase + (size_t)qrow * HDIM + h5 * 8);
    const bf16x8 qf1 = *reinterpret_cast<const bf16x8*>(
        Qbase + (size_t)qrow * HDIM + 16 + h5 * 8);

    // ---- pass 1: softmax denominator (score tile dies each iteration) ----
    float sm0 = 0.f, sm1 = 0.f, sm2 = 0.f, sm3 = 0.f;
#pragma unroll
    for (int tt = 0; tt < 8; ++tt) {
        const int key = tt * 32 + l31;
        const bf16x8 kf0 = *reinterpret_cast<const bf16x8*>(
            &Ks[key * HDIM + ((h5 ^ kmsk) << 3)]);
        const bf16x8 kf1 = *reinterpret_cast<const bf16x8*>(
            &Ks[key * HDIM + (((2 + h5) ^ kmsk) << 3)]);
        f32x16 s = {};
        s = __builtin_amdgcn_mfma_f32_32x32x16_bf16(kf0, qf0, s, 0, 0, 0);
        s = __builtin_amdgcn_mfma_f32_32x32x16_bf16(kf1, qf1, s, 0, 0, 0);
#pragma unroll
        for (int r = 0; r < 16; r += 4) {
            sm0 += __builtin_amdgcn_exp2f(s[r + 0] * c1);
            sm1 += __builtin_amdgcn_exp2f(s[r + 1] * c1);
            sm2 += __builtin_amdgcn_exp2f(s[r + 2] * c1);
            sm3 += __builtin_amdgcn_exp2f(s[r + 3] * c1);
        }
    }
    float sm = (sm0 + sm1) + (sm2 + sm3);
    sm += __shfl_xor(sm, 32, 64);
    const float inv = __builtin_amdgcn_rcpf(sm);

    // ---- pass 2: recompute QK, pack NORMALIZED P (fp32->bf16 once), PV ----
    f32x16 O = {};
#pragma unroll
    for (int tt = 0; tt < 8; ++tt) {
        const int key = tt * 32 + l31;
        const bf16x8 kf0 = *reinterpret_cast<const bf16x8*>(
            &Ks[key * HDIM + ((h5 ^ kmsk) << 3)]);
        const bf16x8 kf1 = *reinterpret_cast<const bf16x8*>(
            &Ks[key * HDIM + (((2 + h5) ^ kmsk) << 3)]);
        f32x16 s = {};
        s = __builtin_amdgcn_mfma_f32_32x32x16_bf16(kf0, qf0, s, 0, 0, 0);
        s = __builtin_amdgcn_mfma_f32_32x32x16_bf16(kf1, qf1, s, 0, 0, 0);

        uint pk8[8];
#pragma unroll
        for (int m = 0; m < 8; ++m) {
            const int r = 4 * (m >> 1) + 2 * (m & 1);
            const float lo = __builtin_amdgcn_exp2f(s[r + 0] * c1) * inv;
            const float hi = __builtin_amdgcn_exp2f(s[r + 1] * c1) * inv;
            uint d;
            asm("v_cvt_pk_bf16_f32 %0, %1, %2" : "=v"(d) : "v"(lo), "v"(hi));
            pk8[m] = d;
        }

        // PV: half of the P-fragment comes from partner lane^32 (r11-verbatim)
#pragma unroll
        for (int k16 = 0; k16 < 2; ++k16) {
            const int mb = 4 * k16;
            const uint s0 = h5 ? pk8[mb + 0] : pk8[mb + 2];
            const uint s1 = h5 ? pk8[mb + 1] : pk8[mb + 3];
            const uint x0 = (uint)__shfl_xor((int)s0, 32, 64);
            const uint x1 = (uint)__shfl_xor((int)s1, 32, 64);
            union { uint u[4]; bf16x8 v; } pw;
            pw.u[0] = h5 ? x0 : pk8[mb + 0];
            pw.u[1] = h5 ? x1 : pk8[mb + 1];
            pw.u[2] = h5 ? pk8[mb + 2] : x0;
            pw.u[3] = h5 ? pk8[mb + 3] : x1;
            const int blk = (4 * tt + 2 * k16 + h5) ^ vmsk;
            const bf16x8 vf = *reinterpret_cast<const bf16x8*>(
                &Vt[l31 * NTOK + blk * 8]);
            O = __builtin_amdgcn_mfma_f32_32x32x16_bf16(pw.v, vf, O, 0, 0, 0);
        }
    }

    // ---- store (r3-verbatim): row=(r&3)+8(r>>2)+4h5, col d=l31 ----
    ushort* obase = att + ((size_t)h * Mtok + winRow + q0) * HDIM + l31;
#pragma unroll
    for (int r = 0; r < 16; ++r) {
        const int qr = (r & 3) + 8 * (r >> 2) + 4 * h5;
        obase[(size_t)qr * HDIM] = f2bf(O[r]);
    }
}

// ---------------- host ----------------
extern "C" void kernel_launch(void* const* d_in, const int* in_sizes, int n_in,
                              void* d_out, int out_size, void* d_ws, size_t ws_size,
                              hipStream_t stream) {
    const float* x     = (const float*)d_in[0];
    const float* w_in  = (const float*)d_in[1];
    const float* b_in  = (const float*)d_in[2];
    const float* w_out = (const float*)d_in[3];

    const int M    = in_sizes[0] / C_DIM;  // 32768 tokens
    const int nWin = M / NTOK;             // 128 windows

    char* ws = (char*)d_ws;
    size_t off = 0;
    ushort* xb    = (ushort*)(ws + off); off += (size_t)M * C_DIM * 2;
    ushort* qkvb  = (ushort*)(ws + off); off += (size_t)M * QKV_DIM * 2;   // [36][M][32]
    ushort* attb  = (ushort*)(ws + off); off += (size_t)M * C_DIM * 2;     // [12][M][32]
    ushort* wqkvb = (ushort*)(ws + off); off += (size_t)QKV_DIM * C_DIM * 2;
    ushort* woutb = (ushort*)(ws + off);

    // single fused convert for x, w_in, w_out (saves 2 launches)
    cvt3_kernel<<<2048, 256, 0, stream>>>(
        x,     xb,    M * C_DIM / 8,
        w_in,  wqkvb, QKV_DIM * C_DIM / 8,
        w_out, woutb, C_DIM * C_DIM / 8);

    // QKV projection -> head-blocked qkv (128x128 tiles)
    gemm_bt_w<1, 0, 0, 1><<<dim3(QKV_DIM / 128, M / 128), 256, 0, stream>>>(
        xb, wqkvb, b_in, qkvb, M, QKV_DIM, C_DIM);

    // fused windowed attention (head-blocked in/out), 8 waves/block
    attn_kernel<<<nWin * NHEAD, 512, 0, stream>>>(qkvb, attb, M);

    // output projection: A head-blocked bf16, fp32 dense out (128x64 tiles)
    gemm_bt<0, 1, 1, 0><<<dim3(C_DIM / 64, M / 128), 256, 0, stream>>>(
        attb, woutb, nullptr, d_out, M, C_DIM, C_DIM);
}

// Round 26
// 114.195 us; speedup vs baseline: 1.1590x; 1.0008x over previous
//
#include <hip/hip_runtime.h>
#include <hip/hip_bf16.h>

typedef __attribute__((ext_vector_type(4)))  float  f32x4;
typedef __attribute__((ext_vector_type(16))) float  f32x16;
typedef __attribute__((ext_vector_type(8)))  short  bf16x8;
typedef __attribute__((ext_vector_type(8)))  ushort u16x8;

#define C_DIM   384
#define QKV_DIM 1152
#define NHEAD   12
#define HDIM    32
#define NTOK    256

__device__ __forceinline__ ushort f2bf(float f) {
    union { __hip_bfloat16 h; ushort u; } cv;
    cv.h = __float2bfloat16(f);
    return cv.u;
}

// ------- fused fp32 -> bf16 convert for THREE tensors (grid-strided) -------
__global__ void cvt3_kernel(const float* __restrict__ s0, ushort* __restrict__ d0, int n0,
                            const float* __restrict__ s1, ushort* __restrict__ d1, int n1,
                            const float* __restrict__ s2, ushort* __restrict__ d2, int n2) {
    const int stride = gridDim.x * blockDim.x;
    const int ntot = n0 + n1 + n2;
    for (int i = blockIdx.x * blockDim.x + threadIdx.x; i < ntot; i += stride) {
        const float* src; ushort* dst; int j;
        if (i < n0)           { src = s0; dst = d0; j = i; }
        else if (i < n0 + n1) { src = s1; dst = d1; j = i - n0; }
        else                  { src = s2; dst = d2; j = i - n0 - n1; }
        const float4 v0 = reinterpret_cast<const float4*>(src)[2 * j];
        const float4 v1 = reinterpret_cast<const float4*>(src)[2 * j + 1];
        union { ushort u[8]; u16x8 v; } o;
        o.u[0] = f2bf(v0.x); o.u[1] = f2bf(v0.y);
        o.u[2] = f2bf(v0.z); o.u[3] = f2bf(v0.w);
        o.u[4] = f2bf(v1.x); o.u[5] = f2bf(v1.y);
        o.u[6] = f2bf(v1.z); o.u[7] = f2bf(v1.w);
        reinterpret_cast<u16x8*>(dst)[j] = o.v;
    }
}

// ---------------- GEMM A: 128x128 tile — used for QKV ----------------
// SINGLE barrier per K-tile: vmcnt(0) [only tile-kt outstanding] -> s_barrier
// [tile visible; all waves' prior-buffer ds_reads executed pre-barrier via the
// compiler's lgkmcnt-before-MFMA waits] -> stage(kt+1 -> cur^1) -> compute.
// Same K-accumulation order as r25 -> bit-identical output.
template<int BIAS, int OUTF32, int AHB, int OHB>
__global__ __launch_bounds__(256, 2) void gemm_bt_w(const ushort* __restrict__ A,
                                                    const ushort* __restrict__ Bw,
                                                    const float* __restrict__ bias,
                                                    void* __restrict__ Cout,
                                                    int M, int N, int K) {
    __shared__ __align__(16) ushort As[2][128 * 64];
    __shared__ __align__(16) ushort Bs[2][128 * 64];

    const int t    = threadIdx.x;
    const int lane = t & 63;
    const int wave = t >> 6;
    const int wr   = (wave >> 1) * 64;
    const int wc   = (wave & 1) * 64;
    const int lr   = lane & 15;
    const int lg   = lane >> 4;

    const int gx  = gridDim.x;
    const int nwg = gx * gridDim.y;
    const int hw  = blockIdx.y * gx + blockIdx.x;
    const int cpx = nwg >> 3;
    const int lin = (hw & 7) * cpx + (hw >> 3);
    const int by  = lin / gx;
    const int bx  = lin - by * gx;
    const int mBase = by * 128;
    const int nBase = bx * 128;

    f32x4 acc[4][4] = {};
    const int nK = K >> 6;

    auto stage = [&](int kt, int c) {               // 8 global_load_lds / thread
        const int k0 = kt << 6;
#pragma unroll
        for (int it = 0; it < 4; ++it) {            // A: 128 rows x 64 k
            const int idx = it * 256 + t;
            const int r   = idx >> 3;
            const int cb  = (idx & 7) ^ (r & 7);
            const ushort* ga;
            if (AHB) {
                const int k = k0 + cb * 8;
                ga = A + ((size_t)(k >> 5) * M + (mBase + r)) * 32 + (k & 31);
            } else {
                ga = A + (size_t)(mBase + r) * K + k0 + cb * 8;
            }
            __builtin_amdgcn_global_load_lds(
                (const __attribute__((address_space(1))) void*)ga,
                (__attribute__((address_space(3))) void*)(&As[c][it * 2048 + wave * 512]),
                16, 0, 0);
        }
#pragma unroll
        for (int it = 0; it < 4; ++it) {            // B: 128 rows x 64 k
            const int idx = it * 256 + t;
            const int r   = idx >> 3;
            const int cb  = (idx & 7) ^ (r & 7);
            const ushort* gb = Bw + (size_t)(nBase + r) * K + k0 + cb * 8;
            __builtin_amdgcn_global_load_lds(
                (const __attribute__((address_space(1))) void*)gb,
                (__attribute__((address_space(3))) void*)(&Bs[c][it * 2048 + wave * 512]),
                16, 0, 0);
        }
    };

    stage(0, 0);
    int cur = 0;

    for (int kt = 0; kt < nK; ++kt) {
        asm volatile("s_waitcnt vmcnt(0)" ::: "memory");  // my tile-kt loads retired
        __builtin_amdgcn_s_barrier();               // all waves: tile-kt visible;
                                                    // cur^1 reads finished pre-barrier
        __builtin_amdgcn_sched_barrier(0);
        if (kt + 1 < nK) stage(kt + 1, cur ^ 1);    // safe: issued after barrier
        __builtin_amdgcn_sched_barrier(0);

#pragma unroll
        for (int kk = 0; kk < 2; ++kk) {
            bf16x8 af[4], bfr[4];
#pragma unroll
            for (int m = 0; m < 4; ++m) {
                const int r = wr + m * 16 + lr;
                af[m] = *reinterpret_cast<const bf16x8*>(
                    &As[cur][r * 64 + (((kk * 4 + lg) ^ (r & 7)) << 3)]);
            }
#pragma unroll
            for (int n = 0; n < 4; ++n) {
                const int r = wc + n * 16 + lr;
                bfr[n] = *reinterpret_cast<const bf16x8*>(
                    &Bs[cur][r * 64 + (((kk * 4 + lg) ^ (r & 7)) << 3)]);
            }
#pragma unroll
            for (int m = 0; m < 4; ++m)
#pragma unroll
                for (int n = 0; n < 4; ++n)
                    acc[m][n] = __builtin_amdgcn_mfma_f32_16x16x32_bf16(af[m], bfr[n], acc[m][n], 0, 0, 0);
        }
        __builtin_amdgcn_sched_barrier(0);          // pin this iteration's LDS reads here
        cur ^= 1;
    }

#pragma unroll
    for (int n = 0; n < 4; ++n) {
        const int col = nBase + wc + n * 16 + lr;
        const float bv = BIAS ? bias[col] : 0.f;
        const int sel  = OHB ? (col / 384) : 0;
        const int c384 = OHB ? (col - sel * 384) : 0;
#pragma unroll
        for (int m = 0; m < 4; ++m) {
            const int row0 = mBase + wr + m * 16 + lg * 4;
#pragma unroll
            for (int j = 0; j < 4; ++j) {
                const float v = acc[m][n][j] + bv;
                const int row = row0 + j;
                if (OUTF32) {
                    reinterpret_cast<float*>(Cout)[(size_t)row * N + col] = v;
                } else if (OHB) {
                    reinterpret_cast<ushort*>(Cout)[
                        ((size_t)(sel * NHEAD + (c384 >> 5)) * M + row) * 32 + (c384 & 31)] = f2bf(v);
                } else {
                    reinterpret_cast<ushort*>(Cout)[(size_t)row * N + col] = f2bf(v);
                }
            }
        }
    }
}

// ---------------- GEMM B: 128x64 tile — used for out-proj ----------------
// Same single-barrier schedule; 6 loads/stage.
template<int BIAS, int OUTF32, int AHB, int OHB>
__global__ __launch_bounds__(256, 3) void gemm_bt(const ushort* __restrict__ A,
                                                  const ushort* __restrict__ Bw,
                                                  const float* __restrict__ bias,
                                                  void* __restrict__ Cout,
                                                  int M, int N, int K) {
    __shared__ __align__(16) ushort As[2][128 * 64];
    __shared__ __align__(16) ushort Bs[2][64 * 64];

    const int t    = threadIdx.x;
    const int lane = t & 63;
    const int wave = t >> 6;
    const int wr   = (wave >> 1) * 64;
    const int wc   = (wave & 1) * 32;
    const int lr   = lane & 15;
    const int lg   = lane >> 4;

    const int gx  = gridDim.x;
    const int nwg = gx * gridDim.y;
    const int hw  = blockIdx.y * gx + blockIdx.x;
    const int cpx = nwg >> 3;
    const int lin = (hw & 7) * cpx + (hw >> 3);
    const int by  = lin / gx;
    const int bx  = lin - by * gx;
    const int mBase = by * 128;
    const int nBase = bx * 64;

    f32x4 acc[4][2] = {};
    const int nK = K >> 6;

    auto stage = [&](int kt, int c) {               // 6 global_load_lds / thread
        const int k0 = kt << 6;
#pragma unroll
        for (int it = 0; it < 4; ++it) {            // A: 128 rows x 64 k
            const int idx = it * 256 + t;
            const int r   = idx >> 3;
            const int cb  = (idx & 7) ^ (r & 7);
            const ushort* ga;
            if (AHB) {
                const int k = k0 + cb * 8;
                ga = A + ((size_t)(k >> 5) * M + (mBase + r)) * 32 + (k & 31);
            } else {
                ga = A + (size_t)(mBase + r) * K + k0 + cb * 8;
            }
            __builtin_amdgcn_global_load_lds(
                (const __attribute__((address_space(1))) void*)ga,
                (__attribute__((address_space(3))) void*)(&As[c][it * 2048 + wave * 512]),
                16, 0, 0);
        }
#pragma unroll
        for (int it = 0; it < 2; ++it) {            // B: 64 rows x 64 k
            const int idx = it * 256 + t;
            const int r   = idx >> 3;
            const int cb  = (idx & 7) ^ (r & 7);
            const ushort* gb = Bw + (size_t)(nBase + r) * K + k0 + cb * 8;
            __builtin_amdgcn_global_load_lds(
                (const __attribute__((address_space(1))) void*)gb,
                (__attribute__((address_space(3))) void*)(&Bs[c][it * 2048 + wave * 512]),
                16, 0, 0);
        }
    };

    stage(0, 0);
    int cur = 0;

    for (int kt = 0; kt < nK; ++kt) {
        asm volatile("s_waitcnt vmcnt(0)" ::: "memory");  // my tile-kt loads retired
        __builtin_amdgcn_s_barrier();
        __builtin_amdgcn_sched_barrier(0);
        if (kt + 1 < nK) stage(kt + 1, cur ^ 1);
        __builtin_amdgcn_sched_barrier(0);

#pragma unroll
        for (int kk = 0; kk < 2; ++kk) {
            bf16x8 af[4], bfr[2];
#pragma unroll
            for (int m = 0; m < 4; ++m) {
                const int r = wr + m * 16 + lr;
                af[m] = *reinterpret_cast<const bf16x8*>(
                    &As[cur][r * 64 + (((kk * 4 + lg) ^ (r & 7)) << 3)]);
            }
#pragma unroll
            for (int n = 0; n < 2; ++n) {
                const int r = wc + n * 16 + lr;
                bfr[n] = *reinterpret_cast<const bf16x8*>(
                    &Bs[cur][r * 64 + (((kk * 4 + lg) ^ (r & 7)) << 3)]);
            }
#pragma unroll
            for (int m = 0; m < 4; ++m)
#pragma unroll
                for (int n = 0; n < 2; ++n)
                    acc[m][n] = __builtin_amdgcn_mfma_f32_16x16x32_bf16(af[m], bfr[n], acc[m][n], 0, 0, 0);
        }
        __builtin_amdgcn_sched_barrier(0);
        cur ^= 1;
    }

#pragma unroll
    for (int n = 0; n < 2; ++n) {
        const int col = nBase + wc + n * 16 + lr;
        const float bv = BIAS ? bias[col] : 0.f;
        const int sel  = OHB ? (col / 384) : 0;
        const int c384 = OHB ? (col - sel * 384) : 0;
#pragma unroll
        for (int m = 0; m < 4; ++m) {
            const int row0 = mBase + wr + m * 16 + lg * 4;
#pragma unroll
            for (int j = 0; j < 4; ++j) {
                const float v = acc[m][n][j] + bv;
                const int row = row0 + j;
                if (OUTF32) {
                    reinterpret_cast<float*>(Cout)[(size_t)row * N + col] = v;
                } else if (OHB) {
                    reinterpret_cast<ushort*>(Cout)[
                        ((size_t)(sel * NHEAD + (c384 >> 5)) * M + row) * 32 + (c384 & 31)] = f2bf(v);
                } else {
                    reinterpret_cast<ushort*>(Cout)[(size_t)row * N + col] = f2bf(v);
                }
            }
        }
    }
}

// ---------------- fused attention: one block per (window, head) ----------------
// r13-VERBATIM (8 waves x 512 threads, one 32-row chunk per wave; two-pass
// recompute, normalized-P single bf16 rounding).
__global__ __launch_bounds__(512) void attn_kernel(const ushort* __restrict__ qkv,
                                                   ushort* __restrict__ att,
                                                   int Mtok) {
    __shared__ __align__(16) ushort Ks[NTOK * HDIM];   // [key][d], swizzled 16B blocks
    __shared__ __align__(16) ushort Vt[HDIM * NTOK];   // [d][key], swizzled 16B blocks

    const int bid = blockIdx.x;
    const int win = bid / NHEAD;
    const int h   = bid % NHEAD;

    const int t    = threadIdx.x;
    const int lane = t & 63;
    const int wave = t >> 6;          // 0..7
    const int l31  = lane & 31;
    const int h5   = lane >> 5;

    const size_t winRow = (size_t)win * NTOK;
    const ushort* Qbase = qkv + ((size_t)h * Mtok + winRow) * HDIM;
    const ushort* Kbase = qkv + ((size_t)(NHEAD + h) * Mtok + winRow) * HDIM;
    const ushort* Vbase = qkv + ((size_t)(2 * NHEAD + h) * Mtok + winRow) * HDIM;

#pragma unroll
    for (int it = 0; it < 2; ++it) {
        const int idx = it * 512 + t;
        const int key = idx >> 2;
        const int cb  = (idx & 3) ^ (key & 3);
        const ushort* gk = Kbase + key * HDIM + cb * 8;
        __builtin_amdgcn_global_load_lds(
            (const __attribute__((address_space(1))) void*)gk,
            (__attribute__((address_space(3))) void*)(&Ks[it * 4096 + wave * 512]),
            16, 0, 0);
    }
#pragma unroll
    for (int it = 0; it < 2; ++it) {
        const int idx = it * 512 + t;
        const int key = idx >> 2;
        const int cb  = idx & 3;
        u16x8 v8 = *reinterpret_cast<const u16x8*>(Vbase + key * HDIM + cb * 8);
#pragma unroll
        for (int jj = 0; jj < 8; ++jj) {
            const int dd  = cb * 8 + jj;
            const int blk = (key >> 3) ^ (dd & 7) ^ ((2 * (dd >> 3)) & 6);
            Vt[dd * NTOK + blk * 8 + (key & 7)] = v8[jj];
        }
    }
    __syncthreads();

    const float c1   = 0.25503509f;                 // 32^-0.5 * log2(e)
    const int   vmsk = (l31 & 7) ^ ((2 * (l31 >> 3)) & 6);
    const int   kmsk = l31 & 3;
    const int   q0   = wave * 32;                   // one 32-row chunk per wave

    const int qrow = q0 + l31;
    const bf16x8 qf0 = *reinterpret_cast<const bf16x8*>(
        Qbase + (size_t)qrow * HDIM + h5 * 8);
    const bf16x8 qf1 = *reinterpret_cast<const bf16x8*>(
        Qbase + (size_t)qrow * HDIM + 16 + h5 * 8);

    // ---- pass 1: softmax denominator (score tile dies each iteration) ----
    float sm0 = 0.f, sm1 = 0.f, sm2 = 0.f, sm3 = 0.f;
#pragma unroll
    for (int tt = 0; tt < 8; ++tt) {
        const int key = tt * 32 + l31;
        const bf16x8 kf0 = *reinterpret_cast<const bf16x8*>(
            &Ks[key * HDIM + ((h5 ^ kmsk) << 3)]);
        const bf16x8 kf1 = *reinterpret_cast<const bf16x8*>(
            &Ks[key * HDIM + (((2 + h5) ^ kmsk) << 3)]);
        f32x16 s = {};
        s = __builtin_amdgcn_mfma_f32_32x32x16_bf16(kf0, qf0, s, 0, 0, 0);
        s = __builtin_amdgcn_mfma_f32_32x32x16_bf16(kf1, qf1, s, 0, 0, 0);
#pragma unroll
        for (int r = 0; r < 16; r += 4) {
            sm0 += __builtin_amdgcn_exp2f(s[r + 0] * c1);
            sm1 += __builtin_amdgcn_exp2f(s[r + 1] * c1);
            sm2 += __builtin_amdgcn_exp2f(s[r + 2] * c1);
            sm3 += __builtin_amdgcn_exp2f(s[r + 3] * c1);
        }
    }
    float sm = (sm0 + sm1) + (sm2 + sm3);
    sm += __shfl_xor(sm, 32, 64);
    const float inv = __builtin_amdgcn_rcpf(sm);

    // ---- pass 2: recompute QK, pack NORMALIZED P (fp32->bf16 once), PV ----
    f32x16 O = {};
#pragma unroll
    for (int tt = 0; tt < 8; ++tt) {
        const int key = tt * 32 + l31;
        const bf16x8 kf0 = *reinterpret_cast<const bf16x8*>(
            &Ks[key * HDIM + ((h5 ^ kmsk) << 3)]);
        const bf16x8 kf1 = *reinterpret_cast<const bf16x8*>(
            &Ks[key * HDIM + (((2 + h5) ^ kmsk) << 3)]);
        f32x16 s = {};
        s = __builtin_amdgcn_mfma_f32_32x32x16_bf16(kf0, qf0, s, 0, 0, 0);
        s = __builtin_amdgcn_mfma_f32_32x32x16_bf16(kf1, qf1, s, 0, 0, 0);

        uint pk8[8];
#pragma unroll
        for (int m = 0; m < 8; ++m) {
            const int r = 4 * (m >> 1) + 2 * (m & 1);
            const float lo = __builtin_amdgcn_exp2f(s[r + 0] * c1) * inv;
            const float hi = __builtin_amdgcn_exp2f(s[r + 1] * c1) * inv;
            uint d;
            asm("v_cvt_pk_bf16_f32 %0, %1, %2" : "=v"(d) : "v"(lo), "v"(hi));
            pk8[m] = d;
        }

        // PV: half of the P-fragment comes from partner lane^32 (r11-verbatim)
#pragma unroll
        for (int k16 = 0; k16 < 2; ++k16) {
            const int mb = 4 * k16;
            const uint s0 = h5 ? pk8[mb + 0] : pk8[mb + 2];
            const uint s1 = h5 ? pk8[mb + 1] : pk8[mb + 3];
            const uint x0 = (uint)__shfl_xor((int)s0, 32, 64);
            const uint x1 = (uint)__shfl_xor((int)s1, 32, 64);
            union { uint u[4]; bf16x8 v; } pw;
            pw.u[0] = h5 ? x0 : pk8[mb + 0];
            pw.u[1] = h5 ? x1 : pk8[mb + 1];
            pw.u[2] = h5 ? pk8[mb + 2] : x0;
            pw.u[3] = h5 ? pk8[mb + 3] : x1;
            const int blk = (4 * tt + 2 * k16 + h5) ^ vmsk;
            const bf16x8 vf = *reinterpret_cast<const bf16x8*>(
                &Vt[l31 * NTOK + blk * 8]);
            O = __builtin_amdgcn_mfma_f32_32x32x16_bf16(pw.v, vf, O, 0, 0, 0);
        }
    }

    // ---- store (r3-verbatim): row=(r&3)+8(r>>2)+4h5, col d=l31 ----
    ushort* obase = att + ((size_t)h * Mtok + winRow + q0) * HDIM + l31;
#pragma unroll
    for (int r = 0; r < 16; ++r) {
        const int qr = (r & 3) + 8 * (r >> 2) + 4 * h5;
        obase[(size_t)qr * HDIM] = f2bf(O[r]);
    }
}

// ---------------- host ----------------
extern "C" void kernel_launch(void* const* d_in, const int* in_sizes, int n_in,
                              void* d_out, int out_size, void* d_ws, size_t ws_size,
                              hipStream_t stream) {
    const float* x     = (const float*)d_in[0];
    const float* w_in  = (const float*)d_in[1];
    const float* b_in  = (const float*)d_in[2];
    const float* w_out = (const float*)d_in[3];

    const int M    = in_sizes[0] / C_DIM;  // 32768 tokens
    const int nWin = M / NTOK;             // 128 windows

    char* ws = (char*)d_ws;
    size_t off = 0;
    ushort* xb    = (ushort*)(ws + off); off += (size_t)M * C_DIM * 2;
    ushort* qkvb  = (ushort*)(ws + off); off += (size_t)M * QKV_DIM * 2;   // [36][M][32]
    ushort* attb  = (ushort*)(ws + off); off += (size_t)M * C_DIM * 2;     // [12][M][32]
    ushort* wqkvb = (ushort*)(ws + off); off += (size_t)QKV_DIM * C_DIM * 2;
    ushort* woutb = (ushort*)(ws + off);

    // single fused convert for x, w_in, w_out
    cvt3_kernel<<<2048, 256, 0, stream>>>(
        x,     xb,    M * C_DIM / 8,
        w_in,  wqkvb, QKV_DIM * C_DIM / 8,
        w_out, woutb, C_DIM * C_DIM / 8);

    // QKV projection -> head-blocked qkv (128x128 tiles, single-barrier loop)
    gemm_bt_w<1, 0, 0, 1><<<dim3(QKV_DIM / 128, M / 128), 256, 0, stream>>>(
        xb, wqkvb, b_in, qkvb, M, QKV_DIM, C_DIM);

    // fused windowed attention (head-blocked in/out), 8 waves/block
    attn_kernel<<<nWin * NHEAD, 512, 0, stream>>>(qkvb, attb, M);

    // output projection: A head-blocked bf16, fp32 dense out (single-barrier loop)
    gemm_bt<0, 1, 1, 0><<<dim3(C_DIM / 64, M / 128), 256, 0, stream>>>(
        attb, woutb, nullptr, d_out, M, C_DIM, C_DIM);
}